// Round 10
// baseline (32.671 us; speedup 1.0000x reference)
//
#include <hip/hip_runtime.h>

// DynamicMaskHead, fused + software-pipelined: per-instance dynamic MLP +
// 4x aligned bilinear + sigmoid in ONE kernel. Block = (instance, 20-row
// chunk) = 2 slabs of 10 rows, double-buffered LDS tile:
//   MLP(s0)->t0 | bar | MLP(s1)->t1 INTERLEAVED WITH store(s0) | bar | store(s1)
// The middle region overlaps HBM stores with VALU/trans compute (R9 was
// phase-locked: serial sum ~32us). MLP body stays straight-line one-quad-
// per-thread (loop-wrapping it spills: R8 256VGPR +112MB scratch).
// Shapes fixed by harness: N=2, Cin=8, H=100, W=152, n_inst=100, stride=8.

#define CIN 8
#define HH 100
#define WW 152
#define HWSZ (HH * WW)
#define NI 100
#define OH (HH * 4)
#define OW (WW * 4)
#define TROWS 10                           // rows per slab
#define SLABS 2                            // slabs per block
#define CROWS (TROWS * SLABS)              // 20 rows per block (HH%CROWS==0)
#define LROWS (TROWS + 2)                  // slab + halo
#define QPR (WW / 4)                       // 38 quads per row
#define NQUADS (LROWS * QPR)               // 456 <= 512: one quad per thread
#define UITEMS (TROWS * WW)                // 1520 upsample items per slab
#define BLOCK 512

__device__ __forceinline__ float fast_rcp(float x) {
    return __builtin_amdgcn_rcpf(x);       // v_rcp_f32, ~1 ulp
}

__device__ __forceinline__ float fast_mish(float x) {
    // mish(x) = x * n/(n+2), n = e(e+2), e = exp(x). For x>20, n/(n+2)==1 in
    // fp32, so clamping only the exp argument keeps it exact and branchless.
    float e = __expf(fminf(x, 20.f));
    float n = e * (e + 2.f);
    return x * n * fast_rcp(n + 2.f);
}

__device__ __forceinline__ float fast_sigmoid(float z) {
    return fast_rcp(1.f + __expf(-z));
}

// MLP for one slab: one 4-px quad per thread, straight-line.
__device__ __forceinline__ void mlp_slab(float tile[LROWS][WW], const float* prm,
                                         const float* fbase, int r0, int t,
                                         float lx, float ly, float inv_soi,
                                         float half, int stride, float dx) {
    if (t >= NQUADS) return;
    const int lr  = t / QPR;               // local row 0..11
    const int qc  = t - lr * QPR;
    const int col = qc * 4;
    const int gr  = min(max(r0 + lr - 1, 0), HH - 1);   // clamped global row

    const float relY = (ly - (float)(gr * stride) - half) * inv_soi;
    const float x0b  = (lx - (float)(col * stride) - half) * inv_soi;

    const float* fb = fbase + gr * WW + col;
    float4 f[CIN];
#pragma unroll
    for (int c = 0; c < CIN; ++c)
        f[c] = *reinterpret_cast<const float4*>(fb + (size_t)c * HWSZ);
#define FEAT(c, j) ((&f[c].x)[(j)])

    // layer 1: 10 -> 8, mish (w1[o][i]=prm[o*10+i], b1=prm[152+o])
    float h1[8][4];
#pragma unroll
    for (int o = 0; o < 8; ++o) {
        float w[10];
#pragma unroll
        for (int i = 0; i < 10; ++i) w[i] = prm[o * 10 + i];
        const float b = prm[152 + o];
#pragma unroll
        for (int j = 0; j < 4; ++j) {
            float acc = fmaf(w[0], x0b + (float)j * dx, fmaf(w[1], relY, b));
#pragma unroll
            for (int c = 0; c < CIN; ++c) acc = fmaf(w[2 + c], FEAT(c, j), acc);
            h1[o][j] = fast_mish(acc);
        }
    }
    // layers 2+3 fused: logit[j] = b3 + sum_o w3[o]*mish(w2[o]·h1[:,j]+b2[o])
    float lo[4];
    const float b3 = prm[168];
#pragma unroll
    for (int j = 0; j < 4; ++j) lo[j] = b3;
#pragma unroll
    for (int o = 0; o < 8; ++o) {
        float w[8];
#pragma unroll
        for (int i = 0; i < 8; ++i) w[i] = prm[80 + o * 8 + i];
        const float b2 = prm[160 + o];
        const float w3 = prm[144 + o];
#pragma unroll
        for (int j = 0; j < 4; ++j) {
            float acc = b2;
#pragma unroll
            for (int i = 0; i < 8; ++i) acc = fmaf(w[i], h1[i][j], acc);
            lo[j] = fmaf(w3, fast_mish(acc), lo[j]);
        }
    }
    *reinterpret_cast<float4*>(&tile[lr][col]) = make_float4(lo[0], lo[1], lo[2], lo[3]);
#undef FEAT
}

// Upsample+sigmoid+store for one slab, from its LDS tile.
// Output row Y=4r+k weights (coord max(Y-2,0)/4, clamped):
//   k=0: .5 prev + .5 cur | k=1: .25 prev + .75 cur | k=2: cur | k=3: .75 cur + .25 next
__device__ __forceinline__ void upsample_slab(const float tile[LROWS][WW],
                                              float* __restrict__ out,
                                              int inst, int r0, int t) {
    for (int b = t; b < UITEMS; b += BLOCK) {
        const int rg = b / WW;             // slab row 0..TROWS-1
        const int cg = b - rg * WW;        // input col
        const int lr = rg + 1;             // center row in tile
        const int gm1 = max(cg - 1, 0), gp1 = min(cg + 1, WW - 1);

        const float v00 = tile[lr - 1][gm1], v01 = tile[lr - 1][cg], v02 = tile[lr - 1][gp1];
        const float v10 = tile[lr    ][gm1], v11 = tile[lr    ][cg], v12 = tile[lr    ][gp1];
        const float v20 = tile[lr + 1][gm1], v21 = tile[lr + 1][cg], v22 = tile[lr + 1][gp1];

        float h0[4], h1[4], h2[4];
        h0[0] = 0.5f * (v00 + v01); h0[1] = fmaf(0.25f, v00, 0.75f * v01); h0[2] = v01; h0[3] = fmaf(0.25f, v02, 0.75f * v01);
        h1[0] = 0.5f * (v10 + v11); h1[1] = fmaf(0.25f, v10, 0.75f * v11); h1[2] = v11; h1[3] = fmaf(0.25f, v12, 0.75f * v11);
        h2[0] = 0.5f * (v20 + v21); h2[1] = fmaf(0.25f, v20, 0.75f * v21); h2[2] = v21; h2[3] = fmaf(0.25f, v22, 0.75f * v21);

        float* O = out + (size_t)inst * (OH * OW) + (size_t)(4 * (r0 + rg)) * OW + 4 * cg;
        float4 row;
        row.x = fast_sigmoid(0.5f * (h0[0] + h1[0]));
        row.y = fast_sigmoid(0.5f * (h0[1] + h1[1]));
        row.z = fast_sigmoid(0.5f * (h0[2] + h1[2]));
        row.w = fast_sigmoid(0.5f * (h0[3] + h1[3]));
        *reinterpret_cast<float4*>(O) = row;
        row.x = fast_sigmoid(fmaf(0.25f, h0[0], 0.75f * h1[0]));
        row.y = fast_sigmoid(fmaf(0.25f, h0[1], 0.75f * h1[1]));
        row.z = fast_sigmoid(fmaf(0.25f, h0[2], 0.75f * h1[2]));
        row.w = fast_sigmoid(fmaf(0.25f, h0[3], 0.75f * h1[3]));
        *reinterpret_cast<float4*>(O + OW) = row;
        row.x = fast_sigmoid(h1[0]);
        row.y = fast_sigmoid(h1[1]);
        row.z = fast_sigmoid(h1[2]);
        row.w = fast_sigmoid(h1[3]);
        *reinterpret_cast<float4*>(O + 2 * OW) = row;
        row.x = fast_sigmoid(fmaf(0.25f, h2[0], 0.75f * h1[0]));
        row.y = fast_sigmoid(fmaf(0.25f, h2[1], 0.75f * h1[1]));
        row.z = fast_sigmoid(fmaf(0.25f, h2[2], 0.75f * h1[2]));
        row.w = fast_sigmoid(fmaf(0.25f, h2[3], 0.75f * h1[3]));
        *reinterpret_cast<float4*>(O + 3 * OW) = row;
    }
}

__global__ void __launch_bounds__(BLOCK)
fused_mask_head_kernel(const float* __restrict__ mask_feats,
                       const float* __restrict__ params,
                       const float* __restrict__ inst_locs,
                       const int* __restrict__ im_inds,
                       const int* __restrict__ fpn_levels,
                       const int* __restrict__ stride_ptr,
                       float* __restrict__ out) {
    __shared__ float prm[169];
    __shared__ float tile[2][LROWS][WW];   // double-buffered logit tiles

    const int inst = blockIdx.y;
    const int base = blockIdx.x * CROWS;   // first row of this block's 20-row chunk
    const int t = threadIdx.x;

    if (t < 169) prm[t] = params[inst * 169 + t];
    __syncthreads();

    // block-uniform instance scalars
    const int stride = stride_ptr[0];
    const float half = (float)(stride / 2);
    const float soi_tab[5] = {64.f, 128.f, 256.f, 512.f, 1024.f};
    const float inv_soi = 1.f / soi_tab[fpn_levels[inst]];
    const float lx = inst_locs[inst * 2 + 0];
    const float ly = inst_locs[inst * 2 + 1];
    const float dx = -(float)stride * inv_soi;
    const float* fbase = mask_feats + (size_t)im_inds[inst] * CIN * HWSZ;

    // prologue: fill tile0
    mlp_slab(tile[0], prm, fbase, base, t, lx, ly, inv_soi, half, stride, dx);
    __syncthreads();

    // middle: compute slab1 into tile1 WHILE storing slab0 from tile0
    // (independent work between the same barriers -> scheduler interleaves,
    //  HBM stores drain under MLP VALU/trans)
    mlp_slab(tile[1], prm, fbase, base + TROWS, t, lx, ly, inv_soi, half, stride, dx);
    upsample_slab(tile[0], out, inst, base, t);
    __syncthreads();

    // epilogue: store slab1
    upsample_slab(tile[1], out, inst, base + TROWS, t);
}

extern "C" void kernel_launch(void* const* d_in, const int* in_sizes, int n_in,
                              void* d_out, int out_size, void* d_ws, size_t ws_size,
                              hipStream_t stream) {
    const float* mask_feats = (const float*)d_in[0];
    const float* params     = (const float*)d_in[1];
    const float* inst_locs  = (const float*)d_in[2];
    const int*   im_inds    = (const int*)d_in[3];
    const int*   fpn_levels = (const int*)d_in[4];
    const int*   stride_ptr = (const int*)d_in[5];
    float* out = (float*)d_out;

    dim3 block(BLOCK);
    dim3 grid(HH / CROWS, NI);             // 5 x 100 = 500 blocks, all resident
    fused_mask_head_kernel<<<grid, block, 0, stream>>>(
        mask_feats, params, inst_locs, im_inds, fpn_levels, stride_ptr, out);
}

// Round 11
// 31.149 us; speedup vs baseline: 1.0488x; 1.0488x over previous
//
#include <hip/hip_runtime.h>

// DynamicMaskHead, fused: per-instance dynamic MLP + 4x aligned bilinear +
// sigmoid in ONE kernel. Block = (instance, 10-row chunk), 512 threads.
// MLP phase = ONE quad per thread, straight-line (loop-wrapping the MLP body
// spills: R8 256VGPR +112MB scratch). __launch_bounds__(512,2) caps VGPR at
// 128 -> 2 blocks (16 waves)/CU; R9/R10 at default allocation sat at ~8
// waves/CU and were latency-bound at ~25% VALU busy (ledger: ~7.7us issue
// vs 32us measured).
// Shapes fixed by harness: N=2, Cin=8, H=100, W=152, n_inst=100, stride=8.

#define CIN 8
#define HH 100
#define WW 152
#define HWSZ (HH * WW)
#define NI 100
#define OH (HH * 4)
#define OW (WW * 4)
#define TROWS 10                           // input rows per block (HH%TROWS==0)
#define LROWS (TROWS + 2)                  // + halo
#define QPR (WW / 4)                       // 38 quads per row
#define NQUADS (LROWS * QPR)               // 456 <= 512: one quad per thread
#define UITEMS (TROWS * WW)                // 1520 upsample work items
#define BLOCK 512

__device__ __forceinline__ float fast_rcp(float x) {
    return __builtin_amdgcn_rcpf(x);       // v_rcp_f32, ~1 ulp
}

__device__ __forceinline__ float fast_mish(float x) {
    // mish(x) = x * n/(n+2), n = e(e+2), e = exp(x). For x>20, n/(n+2)==1 in
    // fp32, so clamping only the exp argument keeps it exact and branchless.
    float e = __expf(fminf(x, 20.f));
    float n = e * (e + 2.f);
    return x * n * fast_rcp(n + 2.f);
}

__device__ __forceinline__ float fast_sigmoid(float z) {
    return fast_rcp(1.f + __expf(-z));
}

__global__ void __launch_bounds__(BLOCK, 2)
fused_mask_head_kernel(const float* __restrict__ mask_feats,
                       const float* __restrict__ params,
                       const float* __restrict__ inst_locs,
                       const int* __restrict__ im_inds,
                       const int* __restrict__ fpn_levels,
                       const int* __restrict__ stride_ptr,
                       float* __restrict__ out) {
    __shared__ float prm[169];
    __shared__ float tile[LROWS][WW];      // logit tile (rows r0-1 .. r0+TROWS, clamped)

    const int inst = blockIdx.y;
    const int r0 = blockIdx.x * TROWS;     // first output-relevant input row
    const int t = threadIdx.x;

    if (t < 169) prm[t] = params[inst * 169 + t];
    __syncthreads();

    // block-uniform instance scalars
    const int stride = stride_ptr[0];
    const float half = (float)(stride / 2);
    const float soi_tab[5] = {64.f, 128.f, 256.f, 512.f, 1024.f};
    const float inv_soi = 1.f / soi_tab[fpn_levels[inst]];
    const float lx = inst_locs[inst * 2 + 0];
    const float ly = inst_locs[inst * 2 + 1];
    const float dx = -(float)stride * inv_soi;   // per-pixel x step
    const float* fbase = mask_feats + (size_t)im_inds[inst] * CIN * HWSZ;

    // ------------- MLP phase: one 4-px quad per thread, straight-line -------------
    if (t < NQUADS) {
        const int lr  = t / QPR;           // local row 0..11
        const int qc  = t - lr * QPR;
        const int col = qc * 4;
        const int gr  = min(max(r0 + lr - 1, 0), HH - 1);   // clamped global row

        const float relY = (ly - (float)(gr * stride) - half) * inv_soi;
        const float x0b  = (lx - (float)(col * stride) - half) * inv_soi;

        const float* fb = fbase + gr * WW + col;
        float4 f[CIN];
#pragma unroll
        for (int c = 0; c < CIN; ++c)
            f[c] = *reinterpret_cast<const float4*>(fb + (size_t)c * HWSZ);
#define FEAT(c, j) ((&f[c].x)[(j)])

        // layer 1: 10 -> 8, mish (w1[o][i]=prm[o*10+i], b1=prm[152+o])
        float h1[8][4];
#pragma unroll
        for (int o = 0; o < 8; ++o) {
            float w[10];
#pragma unroll
            for (int i = 0; i < 10; ++i) w[i] = prm[o * 10 + i];
            const float b = prm[152 + o];
#pragma unroll
            for (int j = 0; j < 4; ++j) {
                float acc = fmaf(w[0], x0b + (float)j * dx, fmaf(w[1], relY, b));
#pragma unroll
                for (int c = 0; c < CIN; ++c) acc = fmaf(w[2 + c], FEAT(c, j), acc);
                h1[o][j] = fast_mish(acc);
            }
        }
        // layers 2+3 fused: logit[j] = b3 + sum_o w3[o]*mish(w2[o]·h1[:,j]+b2[o])
        float lo[4];
        const float b3 = prm[168];
#pragma unroll
        for (int j = 0; j < 4; ++j) lo[j] = b3;
#pragma unroll
        for (int o = 0; o < 8; ++o) {
            float w[8];
#pragma unroll
            for (int i = 0; i < 8; ++i) w[i] = prm[80 + o * 8 + i];
            const float b2 = prm[160 + o];
            const float w3 = prm[144 + o];
#pragma unroll
            for (int j = 0; j < 4; ++j) {
                float acc = b2;
#pragma unroll
                for (int i = 0; i < 8; ++i) acc = fmaf(w[i], h1[i][j], acc);
                lo[j] = fmaf(w3, fast_mish(acc), lo[j]);
            }
        }
        *reinterpret_cast<float4*>(&tile[lr][col]) = make_float4(lo[0], lo[1], lo[2], lo[3]);
#undef FEAT
    }
    __syncthreads();

    // ------------- upsample phase: 1520 4x4 blocks, from LDS tile -------------
    // Output row Y=4r+k weights (coord max(Y-2,0)/4, clamped):
    //   k=0: .5 prev + .5 cur | k=1: .25 prev + .75 cur | k=2: cur | k=3: .75 cur + .25 next
    for (int b = t; b < UITEMS; b += BLOCK) {
        const int rg = b / WW;             // output row group 0..TROWS-1
        const int cg = b - rg * WW;        // input col = output col group
        const int lr = rg + 1;             // center row in tile
        const int gm1 = max(cg - 1, 0), gp1 = min(cg + 1, WW - 1);

        const float v00 = tile[lr - 1][gm1], v01 = tile[lr - 1][cg], v02 = tile[lr - 1][gp1];
        const float v10 = tile[lr    ][gm1], v11 = tile[lr    ][cg], v12 = tile[lr    ][gp1];
        const float v20 = tile[lr + 1][gm1], v21 = tile[lr + 1][cg], v22 = tile[lr + 1][gp1];

        float h0[4], h1[4], h2[4];
        h0[0] = 0.5f * (v00 + v01); h0[1] = fmaf(0.25f, v00, 0.75f * v01); h0[2] = v01; h0[3] = fmaf(0.25f, v02, 0.75f * v01);
        h1[0] = 0.5f * (v10 + v11); h1[1] = fmaf(0.25f, v10, 0.75f * v11); h1[2] = v11; h1[3] = fmaf(0.25f, v12, 0.75f * v11);
        h2[0] = 0.5f * (v20 + v21); h2[1] = fmaf(0.25f, v20, 0.75f * v21); h2[2] = v21; h2[3] = fmaf(0.25f, v22, 0.75f * v21);

        float* O = out + (size_t)inst * (OH * OW) + (size_t)(4 * (r0 + rg)) * OW + 4 * cg;
        float4 row;
        row.x = fast_sigmoid(0.5f * (h0[0] + h1[0]));
        row.y = fast_sigmoid(0.5f * (h0[1] + h1[1]));
        row.z = fast_sigmoid(0.5f * (h0[2] + h1[2]));
        row.w = fast_sigmoid(0.5f * (h0[3] + h1[3]));
        *reinterpret_cast<float4*>(O) = row;
        row.x = fast_sigmoid(fmaf(0.25f, h0[0], 0.75f * h1[0]));
        row.y = fast_sigmoid(fmaf(0.25f, h0[1], 0.75f * h1[1]));
        row.z = fast_sigmoid(fmaf(0.25f, h0[2], 0.75f * h1[2]));
        row.w = fast_sigmoid(fmaf(0.25f, h0[3], 0.75f * h1[3]));
        *reinterpret_cast<float4*>(O + OW) = row;
        row.x = fast_sigmoid(h1[0]);
        row.y = fast_sigmoid(h1[1]);
        row.z = fast_sigmoid(h1[2]);
        row.w = fast_sigmoid(h1[3]);
        *reinterpret_cast<float4*>(O + 2 * OW) = row;
        row.x = fast_sigmoid(fmaf(0.25f, h2[0], 0.75f * h1[0]));
        row.y = fast_sigmoid(fmaf(0.25f, h2[1], 0.75f * h1[1]));
        row.z = fast_sigmoid(fmaf(0.25f, h2[2], 0.75f * h1[2]));
        row.w = fast_sigmoid(fmaf(0.25f, h2[3], 0.75f * h1[3]));
        *reinterpret_cast<float4*>(O + 3 * OW) = row;
    }
}

extern "C" void kernel_launch(void* const* d_in, const int* in_sizes, int n_in,
                              void* d_out, int out_size, void* d_ws, size_t ws_size,
                              hipStream_t stream) {
    const float* mask_feats = (const float*)d_in[0];
    const float* params     = (const float*)d_in[1];
    const float* inst_locs  = (const float*)d_in[2];
    const int*   im_inds    = (const int*)d_in[3];
    const int*   fpn_levels = (const int*)d_in[4];
    const int*   stride_ptr = (const int*)d_in[5];
    float* out = (float*)d_out;

    dim3 block(BLOCK);
    dim3 grid(HH / TROWS, NI);             // 10 x 100 = 1000 blocks
    fused_mask_head_kernel<<<grid, block, 0, stream>>>(
        mask_feats, params, inst_locs, im_inds, fpn_levels, stride_ptr, out);
}